// Round 21
// baseline (634.977 us; speedup 1.0000x reference)
//
#include <hip/hip_runtime.h>
#include <hip/hip_bf16.h>

typedef __attribute__((ext_vector_type(8))) short bf16x8;
typedef __attribute__((ext_vector_type(4))) float f32x4;

#define EMB 256
#define HEADS 8
#define DH 32
#define SEQ 8192
#define BATCH 4
#define NROWS (SEQ*BATCH)
#define FFD 1024
#define DEPTH 4
#define QKVN 768
#define SCALE 0.42044820762685725f
#define NCHUNK 128
#define ROWS_PER_CHUNK (SEQ/NCHUNK)

static __device__ __forceinline__ float bf2f(ushort u){
  union { unsigned int i; float f; } x; x.i = ((unsigned int)u) << 16; return x.f;
}
static __device__ __forceinline__ ushort f2bf(float f){
  union { __hip_bfloat16 h; ushort u; } cv;
  cv.h = __float2bfloat16(f);
  return cv.u;
}
// tanh-form GELU via one v_exp. |err| <= ~3e-3, negligible vs 0.104 threshold.
static __device__ __forceinline__ float gelu_f(float v){
  float y = 0.7978845608028654f * (v + 0.044715f*v*v*v);
  float e = __expf(2.0f*y);
  return 0.5f*v*(1.0f + (1.0f - 2.0f/(e + 1.0f)));
}

// direct HBM->LDS 16B DMA. LDS dest lane-linear; global src pre-swizzled
// (rule #21 both-sides form — validated R4-R20, absmax unchanged).
static __device__ __forceinline__ void gload_lds16(const ushort* g, ushort* l){
  __builtin_amdgcn_global_load_lds(
      (const __attribute__((address_space(1))) unsigned int*)(uintptr_t)g,
      (__attribute__((address_space(3))) unsigned int*)(uintptr_t)l,
      16, 0, 0);
}

// ---------------- weight prep: transpose fp32 [K,N] -> bf16 [N,K] -------------
__global__ __launch_bounds__(256) void prep_weights(
    const float* __restrict__ Wq, const float* __restrict__ Wk,
    const float* __restrict__ Wv, const float* __restrict__ Wo,
    const float* __restrict__ W1, const float* __restrict__ W2,
    ushort* __restrict__ wqkv_t, ushort* __restrict__ wo_t,
    ushort* __restrict__ w1_t, ushort* __restrict__ w2_t)
{
  __shared__ float tile[32][33];
  int bid = blockIdx.x;
  int L = bid / 768, r = bid % 768;
  const float* src; ushort* dst; int K, N, tidx;
  if (r < 192){ int which = r >> 6; tidx = r & 63;
    src = (which==0?Wq:which==1?Wk:Wv) + (long)L*65536;
    dst = wqkv_t + (long)L*QKVN*EMB + which*EMB*EMB; K=256; N=256;
  } else if (r < 256){ tidx = r-192; src = Wo + (long)L*65536; dst = wo_t + (long)L*65536; K=256; N=256; }
  else if (r < 512){ tidx = r-256; src = W1 + (long)L*262144; dst = w1_t + (long)L*262144; K=256; N=1024; }
  else { tidx = r-512; src = W2 + (long)L*262144; dst = w2_t + (long)L*262144; K=1024; N=256; }
  int tn = N >> 5;
  int tk = tidx / tn, tj = tidx % tn;
  int k0 = tk*32, n0 = tj*32;
  int c = threadIdx.x & 31, r0 = threadIdx.x >> 5;
  #pragma unroll
  for (int i=0;i<4;i++){
    int rr = r0 + i*8;
    tile[rr][c] = src[(long)(k0+rr)*N + n0 + c];
  }
  __syncthreads();
  #pragma unroll
  for (int i=0;i<4;i++){
    int rr = r0 + i*8;
    dst[(long)(n0+rr)*K + k0 + c] = f2bf(tile[c][rr]);
  }
}

// ---------------- layernorm (layer-0 prologue only) ---------------------------
__global__ __launch_bounds__(256) void ln_kernel(const float* __restrict__ x,
    const float* __restrict__ g, const float* __restrict__ bb,
    ushort* __restrict__ h)
{
  int wid = threadIdx.x >> 6, lane = threadIdx.x & 63;
  long row = (long)blockIdx.x*4 + wid;
  const float4 xv = *(const float4*)(x + row*EMB + lane*4);
  float s = xv.x+xv.y+xv.z+xv.w;
  float s2 = xv.x*xv.x+xv.y*xv.y+xv.z*xv.z+xv.w*xv.w;
  #pragma unroll
  for (int m=1;m<64;m<<=1){ s += __shfl_xor(s,m,64); s2 += __shfl_xor(s2,m,64); }
  float mean = s * (1.0f/EMB);
  float inv = rsqrtf(s2*(1.0f/EMB) - mean*mean + 1e-5f);
  float4 gv = *(const float4*)(g + lane*4);
  float4 bv = *(const float4*)(bb + lane*4);
  ushort4 o;
  o.x = f2bf((xv.x-mean)*inv*gv.x + bv.x);
  o.y = f2bf((xv.y-mean)*inv*gv.y + bv.y);
  o.z = f2bf((xv.z-mean)*inv*gv.z + bv.z);
  o.w = f2bf((xv.w-mean)*inv*gv.w + bv.w);
  *(ushort4*)(h + row*EMB + lane*4) = o;
}

// ---------------- GEMM MODE0 (QKV): C[M,N] = A[M,K] @ Bt[N,K]^T --------------
// Proven R13 structure, R20 BN=256 retile. GSWAP=1: A-panel L2 locality.
template<int MODE, int BM, int BN, int BK, int GSWAP>
__global__ __launch_bounds__(512, 2) void gemm_bt(
    const ushort* __restrict__ A, const ushort* __restrict__ Bt,
    int M, int N, int K,
    ushort* __restrict__ outb)
{
  constexpr int NF = BN/64;
  constexpr int MR = BM/32;
  constexpr int MH = MR/4;
  constexpr int KK = BK/32;
  constexpr int CPR = BK/8;
  constexpr int AI = BM*BK/4096;
  constexpr int BI = BN*BK/4096;
  constexpr int TI = AI + BI;
  constexpr int NPH = KK*MH;
  __shared__ ushort LDSraw[2*BM*BK + 2*BN*BK];
  ushort* Abuf0 = LDSraw;
  ushort* Abuf1 = LDSraw + BM*BK;
  ushort* Bbuf0 = LDSraw + 2*BM*BK;
  ushort* Bbuf1 = LDSraw + 2*BM*BK + BN*BK;
  int t = threadIdx.x;
  int lane = t & 63, wid = t >> 6;
  int wr = wid >> 2, wc = wid & 3;
  int wrb = wr*(BM/2), wcb = wc*(BN/4);
  long rowA0, colB0;
  if (GSWAP){ rowA0 = (long)blockIdx.y * BM; colB0 = (long)blockIdx.x * BN; }
  else      { rowA0 = (long)blockIdx.x * BM; colB0 = (long)blockIdx.y * BN; }
  const ushort* gA[AI]; int dA[AI];
  #pragma unroll
  for (int i=0;i<AI;i++){
    int l = i*512 + t;
    int row = l / CPR;
    int clog = (t % CPR) ^ (row & (CPR-1));
    gA[i] = A + (rowA0 + row)*(long)K + clog*8;
    dA[i] = l*8;
  }
  const ushort* gB[BI]; int dB[BI];
  #pragma unroll
  for (int i=0;i<BI;i++){
    int l = i*512 + t;
    int row = l / CPR;
    int clog = (t % CPR) ^ (row & (CPR-1));
    gB[i] = Bt + (colB0 + row)*(long)K + clog*8;
    dB[i] = l*8;
  }
  ushort* Ac = Abuf0; ushort* An = Abuf1;
  ushort* Bc = Bbuf0; ushort* Bn = Bbuf1;
  f32x4 acc[MR][NF] = {};
  int fr = lane & 15, cr4 = lane >> 4;
  int nsteps = K / BK;
  #pragma unroll
  for (int i=0;i<AI;i++) gload_lds16(gA[i], Ac + dA[i]);
  #pragma unroll
  for (int i=0;i<BI;i++) gload_lds16(gB[i], Bc + dB[i]);
  asm volatile("s_waitcnt vmcnt(0)" ::: "memory");
  __syncthreads();
  for (int s = 0; s < nsteps; ++s){
    bool pf = (s+1 < nsteps);
    long knext = (long)(s+1) * BK;
    #pragma unroll
    for (int kk=0; kk<KK; ++kk){
      int chunk = (((kk*4 + cr4)) ^ (fr & (CPR-1))) << 3;
      bf16x8 bv[NF];
      #pragma unroll
      for (int n=0;n<NF;n++)
        bv[n] = *(const bf16x8*)(Bc + (wcb + n*16 + fr)*BK + chunk);
      #pragma unroll
      for (int mh=0; mh<MH; ++mh){
        int sp = kk*MH + mh;
        bf16x8 av[4];
        #pragma unroll
        for (int m=0;m<4;m++)
          av[m] = *(const bf16x8*)(Ac + (wrb + (mh*4+m)*16 + fr)*BK + chunk);
        if (pf){
          #pragma unroll
          for (int j=0;j<TI;j++){
            if (j*NPH >= sp*TI && j*NPH < (sp+1)*TI){
              if (j < AI) gload_lds16(gA[j]+knext, An+dA[j]);
              else        gload_lds16(gB[j-AI]+knext, Bn+dB[j-AI]);
            }
          }
        }
        __builtin_amdgcn_s_setprio(1);
        #pragma unroll
        for (int m=0;m<4;m++){
          #pragma unroll
          for (int n=0;n<NF;n++)
            acc[mh*4+m][n] = __builtin_amdgcn_mfma_f32_16x16x32_bf16(av[m], bv[n], acc[mh*4+m][n], 0,0,0);
        }
        __builtin_amdgcn_s_setprio(0);
      }
    }
    asm volatile("s_waitcnt vmcnt(0)" ::: "memory");
    __syncthreads();
    ushort* tp;
    tp = Ac; Ac = An; An = tp;
    tp = Bc; Bc = Bn; Bn = tp;
  }
  constexpr int BNP = BN + 4;
  constexpr int ROUNDS = BM/32;
  constexpr int RPH = BM/64;
  float* bounce = (float*)LDSraw;
  int fq = lane >> 4;
  constexpr int TPR = BN/4;
  int rdrow = t / TPR;
  int rdcol = (t % TPR) * 4;
  constexpr int RPP = 512 / TPR;
  constexpr int PASSES = 32 / RPP;
  long gcf = colB0 + rdcol;
  #pragma unroll
  for (int r = 0; r < ROUNDS; ++r){
    __syncthreads();
    if (wr == r / RPH){
      int mb = (r % RPH)*2;
      #pragma unroll
      for (int m4=0;m4<2;m4++){
        #pragma unroll
        for (int n=0;n<NF;n++){
          #pragma unroll
          for (int i=0;i<4;i++)
            bounce[(m4*16 + fq*4 + i)*BNP + wcb + n*16 + fr] = acc[mb+m4][n][i];
        }
      }
    }
    __syncthreads();
    long gr0 = rowA0 + r*32;
    #pragma unroll
    for (int p=0;p<PASSES;p++){
      int lr = p*RPP + rdrow;
      long gr = gr0 + lr;
      float4 v = *(float4*)&bounce[lr*BNP + rdcol];
      ushort4 o; o.x=f2bf(v.x); o.y=f2bf(v.y); o.z=f2bf(v.z); o.w=f2bf(v.w);
      *(ushort4*)&outb[gr*N + gcf] = o;
    }
  }
}

// ---------------- fused Wo + FF layer-tail -----------------------------------
// Per 128-row block: [Wo GEMM, A resident in As] -> epilogue-W (residual+LN2,
// h2 written straight into As in FF swizzle layout; xmid residual to global)
// -> FF chunks (R15-proven body) -> FF epilogue (residual + LN1-next or fp32).
// WMODE 3: Wo residual in fp32 (x_in); 4: bf16 (xb).
// FMODE 4: write xb(bf16)+h1_next with LN; 5: write fp32 final, no LN.
template<int WMODE, int FMODE>
__global__ __launch_bounds__(512) void wo_ff_fused(
    const ushort* __restrict__ aattn, const ushort* __restrict__ wot,
    const ushort* __restrict__ w1t, const ushort* __restrict__ w2t,
    const float* __restrict__ bo_, const float* __restrict__ b1,
    const float* __restrict__ b2,
    const float* __restrict__ xinf, const ushort* __restrict__ xinb,
    ushort* __restrict__ xmid,
    float* __restrict__ xoutf, ushort* __restrict__ xoutb,
    ushort* __restrict__ hout,
    const float* __restrict__ ln2g, const float* __restrict__ ln2b,
    const float* __restrict__ ln1g_, const float* __restrict__ ln1b_)
{
  __shared__ ushort LDS[74240];      // 145 KB total
  ushort* As = LDS;                  // 64 KB: Aattn -> h2 -> f32 bounce (FF epi)
  ushort* R1 = LDS + 32768;          // 32 KB: Wo dbuf0 / W1b
  ushort* R2 = LDS + 49152;          // 32 KB: Wo dbuf1 / W2b
  ushort* Ps = LDS + 65536;          // 17 KB: epi-W bounce (16x260 f32) / FF Ps
  int t = threadIdx.x, lane = t & 63, wid = t >> 6;
  int fr = lane & 15, cr4 = lane >> 4, fq = lane >> 4;
  long rowA0 = (long)blockIdx.x * 128;
  // ---------------- Wo phase: accW[128][256] = Aattn @ WoT^T ----------------
  int wr = wid >> 2, wc = wid & 3;
  int wrb = wr*64, wcb = wc*64;
  // prologue: stage Aattn (once, swizzle row&31) + Wo chunk 0 (swizzle row&7)
  #pragma unroll
  for (int i=0;i<8;i++){
    int l = i*512 + t;
    int row = l >> 5;
    int clog = (l & 31) ^ (row & 31);
    gload_lds16(aattn + (rowA0+row)*256 + clog*8, As + l*8);
  }
  #pragma unroll
  for (int i=0;i<4;i++){
    int l = i*512 + t;
    int row = l >> 3;
    int clog = (l & 7) ^ (row & 7);
    gload_lds16(wot + row*256 + clog*8, R1 + l*8);
  }
  asm volatile("s_waitcnt vmcnt(0)" ::: "memory");
  __syncthreads();
  f32x4 accW[4][4] = {};
  for (int c = 0; c < 4; ++c){
    const ushort* Wc = (c&1) ? R2 : R1;
    ushort* Wn = (c&1) ? R1 : R2;
    #pragma unroll
    for (int kk=0; kk<2; ++kk){
      if (kk==0 && c<3){
        #pragma unroll
        for (int i=0;i<4;i++){
          int l = i*512 + t;
          int row = l >> 3;
          int clog = (l & 7) ^ (row & 7);
          gload_lds16(wot + row*256 + (c+1)*64 + clog*8, Wn + l*8);
        }
      }
      int ci2 = kk*4 + cr4;                 // 0..7
      bf16x8 av[4], bv[4];
      #pragma unroll
      for (int m=0;m<4;m++){
        int row = wrb + m*16 + fr;
        int gc2 = c*8 + ci2;
        av[m] = *(const bf16x8*)(As + row*256 + ((gc2 ^ (row&31)) << 3));
      }
      #pragma unroll
      for (int n=0;n<4;n++){
        int row = wcb + n*16 + fr;
        bv[n] = *(const bf16x8*)(Wc + row*64 + ((ci2 ^ (row&7)) << 3));
      }
      __builtin_amdgcn_s_setprio(1);
      #pragma unroll
      for (int m=0;m<4;m++){
        #pragma unroll
        for (int n=0;n<4;n++)
          accW[m][n] = __builtin_amdgcn_mfma_f32_16x16x32_bf16(av[m], bv[n], accW[m][n], 0,0,0);
      }
      __builtin_amdgcn_s_setprio(0);
    }
    asm volatile("s_waitcnt vmcnt(0)" ::: "memory");
    __syncthreads();
  }
  // stage W1(0) into R1 (drained before FF chunk 0; covered by epilogue-W)
  #pragma unroll
  for (int i=0;i<4;i++){
    int l = i*512 + t;
    int row = l >> 5;
    int clog = (l & 31) ^ (row & 31);
    gload_lds16(w1t + row*256 + clog*8, R1 + l*8);
  }
  // ------------- epilogue-W: residual + LN2; h2 -> As (FF layout) -----------
  {
    float* wb = (float*)Ps;              // 16 x 260 f32
    int rdrow = t >> 6;                  // 0..7 (one wave per row)
    int rdcol = (t & 63) * 4;
    const float4 bo4 = *(const float4*)&bo_[rdcol];
    const float4 g4 = *(const float4*)&ln2g[rdcol];
    const float4 bb4 = *(const float4*)&ln2b[rdcol];
    #pragma unroll
    for (int r = 0; r < 8; ++r){
      __syncthreads();
      if (wr == (r >> 2)){
        int m = r & 3;
        #pragma unroll
        for (int n=0;n<4;n++){
          #pragma unroll
          for (int i2=0;i2<4;i2++)
            wb[(fq*4 + i2)*260 + wcb + n*16 + fr] = accW[m][n][i2];
        }
      }
      __syncthreads();
      #pragma unroll
      for (int p=0;p<2;p++){
        int lr = p*8 + rdrow;
        int row = r*16 + lr;             // block-local row
        long gr = rowA0 + row;
        float4 v = *(float4*)&wb[lr*260 + rdcol];
        float xo0, xo1, xo2, xo3;
        if (WMODE==3){
          const float4 xo = *(const float4*)&xinf[gr*EMB + rdcol];
          xo0=xo.x; xo1=xo.y; xo2=xo.z; xo3=xo.w;
        } else {
          const ushort4 xb4 = *(const ushort4*)&xinb[gr*EMB + rdcol];
          xo0=bf2f(xb4.x); xo1=bf2f(xb4.y); xo2=bf2f(xb4.z); xo3=bf2f(xb4.w);
        }
        v.x += bo4.x + xo0; v.y += bo4.y + xo1;
        v.z += bo4.z + xo2; v.w += bo4.w + xo3;
        ushort4 xw;
        xw.x=f2bf(v.x); xw.y=f2bf(v.y); xw.z=f2bf(v.z); xw.w=f2bf(v.w);
        *(ushort4*)&xmid[gr*EMB + rdcol] = xw;
        float s1 = v.x+v.y+v.z+v.w;
        float s2 = v.x*v.x+v.y*v.y+v.z*v.z+v.w*v.w;
        #pragma unroll
        for (int mm=1;mm<64;mm<<=1){ s1 += __shfl_xor(s1,mm,64); s2 += __shfl_xor(s2,mm,64); }
        float mean = s1 * (1.0f/EMB);
        float inv = rsqrtf(s2*(1.0f/EMB) - mean*mean + 1e-5f);
        ushort4 hx;
        hx.x = f2bf((v.x-mean)*inv*g4.x + bb4.x);
        hx.y = f2bf((v.y-mean)*inv*g4.y + bb4.y);
        hx.z = f2bf((v.z-mean)*inv*g4.z + bb4.z);
        hx.w = f2bf((v.w-mean)*inv*g4.w + bb4.w);
        int phys = (rdcol >> 3) ^ (row & 31);
        *(ushort4*)&As[row*256 + phys*8 + (rdcol & 7)] = hx;
      }
    }
  }
  asm volatile("s_waitcnt vmcnt(0)" ::: "memory");   // W1(0) staged
  __syncthreads();
  // ---------------- FF phase (R15-proven body; A=h2 in As) ------------------
  int rwP = (wid & 3)*32, fwP = (wid >> 2)*32;
  int rw2 = (wid >> 2)*64, cw2 = (wid & 3)*64;
  f32x4 accC[4][4] = {};
  for (int j = 0; j < 16; ++j){
    float bvp0 = b1[j*64 + fwP + fr];
    float bvp1 = b1[j*64 + fwP + 16 + fr];
    f32x4 accP[2][2] = {};
    #pragma unroll
    for (int kk=0; kk<8; ++kk){
      if (kk < 4){                           // front-load all 4 W2c issues
        int l = kk*512 + t;
        int row = l >> 3, c = l & 7;
        int clog = c ^ (row & 7);
        gload_lds16(w2t + row*1024 + j*64 + clog*8, R2 + l*8);
      }
      int ci = kk*4 + cr4;
      bf16x8 av[2], wv[2];
      #pragma unroll
      for (int m=0;m<2;m++){
        int row = rwP + m*16 + fr;
        av[m] = *(const bf16x8*)(As + row*256 + ((ci ^ (row&31)) << 3));
      }
      #pragma unroll
      for (int n=0;n<2;n++){
        int row = fwP + n*16 + fr;
        wv[n] = *(const bf16x8*)(R1 + row*256 + ((ci ^ (row&31)) << 3));
      }
      __builtin_amdgcn_s_setprio(1);
      #pragma unroll
      for (int m=0;m<2;m++){
        #pragma unroll
        for (int n=0;n<2;n++)
          accP[m][n] = __builtin_amdgcn_mfma_f32_16x16x32_bf16(av[m], wv[n], accP[m][n], 0,0,0);
      }
      __builtin_amdgcn_s_setprio(0);
    }
    #pragma unroll
    for (int n=0;n<2;n++){
      float bv = (n==0) ? bvp0 : bvp1;
      #pragma unroll
      for (int m=0;m<2;m++){
        #pragma unroll
        for (int i2=0;i2<4;i2++){
          int row = rwP + m*16 + fq*4 + i2;
          Ps[row*68 + fwP + n*16 + fr] = f2bf(gelu_f(accP[m][n][i2] + bv));
        }
      }
    }
    asm volatile("s_waitcnt vmcnt(0)" ::: "memory");
    __syncthreads();
    bool pw1 = (j+1 < 16);
    #pragma unroll
    for (int kk2=0; kk2<2; ++kk2){
      if (pw1 && kk2==0){                    // front-load all 4 W1c issues
        #pragma unroll
        for (int ii=0;ii<4;ii++){
          int l = ii*512 + t;
          int row = l >> 5;
          int clog = (l & 31) ^ (row & 31);
          gload_lds16(w1t + (long)(j+1)*16384 + row*256 + clog*8, R1 + l*8);
        }
      }
      int ci2 = kk2*4 + cr4;
      bf16x8 pv[4], wv2[4];
      #pragma unroll
      for (int m=0;m<4;m++){
        int row = rw2 + m*16 + fr;
        pv[m] = *(const bf16x8*)(Ps + row*68 + ci2*8);
      }
      #pragma unroll
      for (int n=0;n<4;n++){
        int row = cw2 + n*16 + fr;
        wv2[n] = *(const bf16x8*)(R2 + row*64 + ((ci2 ^ (row&7)) << 3));
      }
      __builtin_amdgcn_s_setprio(1);
      #pragma unroll
      for (int m=0;m<4;m++){
        #pragma unroll
        for (int n=0;n<4;n++)
          accC[m][n] = __builtin_amdgcn_mfma_f32_16x16x32_bf16(pv[m], wv2[n], accC[m][n], 0,0,0);
      }
      __builtin_amdgcn_s_setprio(0);
    }
    asm volatile("s_waitcnt vmcnt(0)" ::: "memory");
    __syncthreads();
  }
  // ---------------- FF epilogue: residual (+LN1-next) -----------------------
  {
    float* bounce = (float*)As;            // h2 dead now
    int rdrow = t >> 6;
    int rdcol = (t & 63) * 4;
    const float4 bv4 = *(const float4*)&b2[rdcol];
    float4 g4 = {0,0,0,0}, b4 = {0,0,0,0};
    if (FMODE==4){ g4 = *(const float4*)&ln1g_[rdcol]; b4 = *(const float4*)&ln1b_[rdcol]; }
    #pragma unroll
    for (int r = 0; r < 4; ++r){
      __syncthreads();
      if ((wid >> 2) == (r >> 1)){
        int mb = (r & 1)*2;
        #pragma unroll
        for (int m4=0;m4<2;m4++){
          #pragma unroll
          for (int n=0;n<4;n++){
            #pragma unroll
            for (int i2=0;i2<4;i2++)
              bounce[(m4*16 + fq*4 + i2)*260 + cw2 + n*16 + fr] = accC[mb+m4][n][i2];
          }
        }
      }
      __syncthreads();
      long gr0 = rowA0 + r*32;
      #pragma unroll
      for (int p=0;p<4;p++){
        int lr = p*8 + rdrow;
        long gr = gr0 + lr;
        float4 v = *(float4*)&bounce[lr*260 + rdcol];
        const ushort4 xb4 = *(const ushort4*)&xmid[gr*EMB + rdcol];
        v.x += bv4.x + bf2f(xb4.x); v.y += bv4.y + bf2f(xb4.y);
        v.z += bv4.z + bf2f(xb4.z); v.w += bv4.w + bf2f(xb4.w);
        if (FMODE==5){
          *(float4*)&xoutf[gr*EMB + rdcol] = v;
        } else {
          ushort4 xw;
          xw.x=f2bf(v.x); xw.y=f2bf(v.y); xw.z=f2bf(v.z); xw.w=f2bf(v.w);
          *(ushort4*)&xoutb[gr*EMB + rdcol] = xw;
          float s1 = v.x+v.y+v.z+v.w;
          float s2 = v.x*v.x+v.y*v.y+v.z*v.z+v.w*v.w;
          #pragma unroll
          for (int mm=1;mm<64;mm<<=1){ s1 += __shfl_xor(s1,mm,64); s2 += __shfl_xor(s2,mm,64); }
          float mean = s1 * (1.0f/EMB);
          float inv = rsqrtf(s2*(1.0f/EMB) - mean*mean + 1e-5f);
          ushort4 o;
          o.x = f2bf((v.x-mean)*inv*g4.x + b4.x);
          o.y = f2bf((v.y-mean)*inv*g4.y + b4.y);
          o.z = f2bf((v.z-mean)*inv*g4.z + b4.z);
          o.w = f2bf((v.w-mean)*inv*g4.w + b4.w);
          *(ushort4*)&hout[gr*EMB + rdcol] = o;
        }
      }
    }
  }
}

// ---------------- k-softmax column stats, chunked over n ----------------------
__global__ __launch_bounds__(256) void colstats_partial(const ushort* __restrict__ qkv,
    float* __restrict__ pmax, float* __restrict__ psum)
{
  int ch = blockIdx.x, b = blockIdx.y;
  int t = threadIdx.x;
  const ushort* base = qkv + ((long)b*SEQ + (long)ch*ROWS_PER_CHUNK)*QKVN + EMB + t;
  float m[4] = {-1e30f,-1e30f,-1e30f,-1e30f};
  float s[4] = {0.f,0.f,0.f,0.f};
  #pragma unroll 2
  for (int n = 0; n < ROWS_PER_CHUNK; n += 4){
    #pragma unroll
    for (int j=0;j<4;j++){
      float v = bf2f(base[(long)(n+j)*QKVN]) * SCALE;
      float m2 = fmaxf(m[j], v);
      s[j] = s[j]*__expf(m[j]-m2) + __expf(v-m2);
      m[j] = m2;
    }
  }
  float M = fmaxf(fmaxf(m[0],m[1]), fmaxf(m[2],m[3]));
  float S = s[0]*__expf(m[0]-M) + s[1]*__expf(m[1]-M)
          + s[2]*__expf(m[2]-M) + s[3]*__expf(m[3]-M);
  long idx = ((long)b*NCHUNK + ch)*EMB + t;
  pmax[idx] = M; psum[idx] = S;
}

__global__ __launch_bounds__(256) void colstats_reduce(const float* __restrict__ pmax,
    const float* __restrict__ psum, float* __restrict__ kmax, float* __restrict__ ksum)
{
  int b = blockIdx.x, t = threadIdx.x;
  const float* pm = pmax + (long)b*NCHUNK*EMB + t;
  const float* ps = psum + (long)b*NCHUNK*EMB + t;
  float m = -1e30f, s = 0.f;
  for (int c = 0; c < NCHUNK; ++c){
    float cm = pm[(long)c*EMB], cs = ps[(long)c*EMB];
    float m2 = fmaxf(m, cm);
    s = s*__expf(m-m2) + cs*__expf(cm-m2);
    m = m2;
  }
  kmax[b*EMB + t] = m;
  ksum[b*EMB + t] = s;
}

// ---------------- context partials: ctx_part[b][h][chunk][d][e] --------------
__global__ __launch_bounds__(256) void ctx_partial(
    const ushort* __restrict__ qkv, const float* __restrict__ kmax,
    float* __restrict__ ctx_part)
{
  constexpr int LT = 72;
  __shared__ ushort ekT[32*LT];
  __shared__ ushort vvT[32*LT];
  int ch = blockIdx.x, h = blockIdx.y, b = blockIdx.z;
  int t = threadIdx.x, lane = t & 63, wid = t >> 6;
  long nbase = (long)b*SEQ + ch*512;
  int lrow = t >> 2, lseg = (t & 3) << 3;
  float km[8];
  #pragma unroll
  for (int j=0;j<8;j++) km[j] = kmax[b*256 + h*DH + lseg + j];
  int wstep = wid & 1, wdr = (wid >> 1) << 4;
  f32x4 acc0 = {}, acc1 = {};
  int frow = lane & 15, g8 = (lane >> 4) << 3;
  for (int st = 0; st < 8; ++st){
    long n0 = nbase + st*64;
    const ushort* gk = qkv + (n0 + lrow)*QKVN + EMB + h*DH + lseg;
    uint4 kv = *(const uint4*)gk;
    uint4 vv = *(const uint4*)(gk + EMB);
    __syncthreads();
    const ushort* kp = (const ushort*)&kv;
    const ushort* vp = (const ushort*)&vv;
    #pragma unroll
    for (int j=0;j<8;j++){
      float f = bf2f(kp[j])*SCALE;
      ekT[(lseg+j)*LT + lrow] = f2bf(__expf(f - km[j]));
      vvT[(lseg+j)*LT + lrow] = vp[j];
    }
    __syncthreads();
    bf16x8 afr = *(const bf16x8*)(ekT + (wdr + frow)*LT + wstep*32 + g8);
    bf16x8 bf0 = *(const bf16x8*)(vvT + frow*LT + wstep*32 + g8);
    bf16x8 bf1 = *(const bf16x8*)(vvT + (16 + frow)*LT + wstep*32 + g8);
    acc0 = __builtin_amdgcn_mfma_f32_16x16x32_bf16(afr, bf0, acc0, 0,0,0);
    acc1 = __builtin_amdgcn_mfma_f32_16x16x32_bf16(afr, bf1, acc1, 0,0,0);
  }
  int fq = lane >> 4;
  long pb = (((long)(b*HEADS+h))*32 + (ch*2+wstep))*1024;
  #pragma unroll
  for (int i=0;i<4;i++){
    ctx_part[pb + (wdr + fq*4 + i)*32 + frow] = acc0[i];
    ctx_part[pb + (wdr + fq*4 + i)*32 + 16 + frow] = acc1[i];
  }
}

// ---------------- context reduce + 1/ksum + write transposed bf16 ------------
__global__ __launch_bounds__(256) void ctx_reduce(const float* __restrict__ ctx_part,
    const float* __restrict__ ksum, ushort* __restrict__ ctxT)
{
  int bh = blockIdx.x; int b = bh >> 3, h = bh & 7;
  int t = threadIdx.x; int d = t >> 3, e4 = (t & 7) << 2;
  const float* p = ctx_part + (long)bh*32768 + d*32 + e4;
  float sx=0, sy=0, sz=0, sw=0;
  for (int c=0;c<32;c++){
    const float4 v = *(const float4*)(p + c*1024);
    sx+=v.x; sy+=v.y; sz+=v.z; sw+=v.w;
  }
  float inv = 1.0f / ksum[b*256 + h*DH + d];
  long base = (long)bh*1024;
  ctxT[base + (e4+0)*32 + d] = f2bf(sx*inv);
  ctxT[base + (e4+1)*32 + d] = f2bf(sy*inv);
  ctxT[base + (e4+2)*32 + d] = f2bf(sz*inv);
  ctxT[base + (e4+3)*32 + d] = f2bf(sw*inv);
}

// ---------------- q-softmax @ ctx -> ao (bf16) -------------------------------
__global__ __launch_bounds__(256) void attn_out(
    const ushort* __restrict__ qkv, const ushort* __restrict__ ctxT,
    ushort* __restrict__ ao)
{
  __shared__ ushort sq[4][16][264];
  int t = threadIdx.x, lane = t & 63, wid = t >> 6;
  long row0 = (long)blockIdx.x*64 + wid*16;
  int b = (int)(row0 / SEQ);
  int fr = lane & 15, g = lane >> 4;
  bf16x8 cf[8][2];
  #pragma unroll
  for (int h=0;h<8;h++){
    #pragma unroll
    for (int eh=0;eh<2;eh++)
      cf[h][eh] = *(const bf16x8*)(ctxT + ((long)(b*8+h)*32 + eh*16 + fr)*32 + g*8);
  }
  long gr = row0 + fr;
  #pragma unroll
  for (int hh=0;hh<2;hh++){
    int h = g*2 + hh;
    const ushort* qp = qkv + gr*QKVN + h*DH;
    union { uint4 v[4]; ushort u[32]; } qq;
    qq.v[0]=*(const uint4*)qp; qq.v[1]=*(const uint4*)(qp+8);
    qq.v[2]=*(const uint4*)(qp+16); qq.v[3]=*(const uint4*)(qp+24);
    float f[32]; float m = -1e30f;
    #pragma unroll
    for (int j=0;j<32;j++){ f[j] = bf2f(qq.u[j])*SCALE; m = fmaxf(m, f[j]); }
    float ssum = 0.f;
    #pragma unroll
    for (int j=0;j<32;j++){ f[j] = __expf(f[j]-m); ssum += f[j]; }
    float inv = 1.0f/ssum;
    union { uint4 v[4]; ushort u[32]; } oo;
    #pragma unroll
    for (int j=0;j<32;j++) oo.u[j] = f2bf(f[j]*inv);
    ushort* dst = &sq[wid][fr][h*DH];
    #pragma unroll
    for (int c2=0;c2<4;c2++) *(uint4*)(dst + c2*8) = oo.v[c2];
  }
  __syncthreads();
  #pragma unroll
  for (int h=0;h<8;h++){
    bf16x8 af = *(const bf16x8*)(&sq[wid][fr][h*DH + g*8]);
    f32x4 z = {};
    f32x4 o0 = __builtin_amdgcn_mfma_f32_16x16x32_bf16(af, cf[h][0], z, 0,0,0);
    f32x4 o1 = __builtin_amdgcn_mfma_f32_16x16x32_bf16(af, cf[h][1], z, 0,0,0);
    #pragma unroll
    for (int i=0;i<4;i++){
      long r = row0 + g*4 + i;
      ao[r*EMB + h*DH + fr]      = f2bf(o0[i]);
      ao[r*EMB + h*DH + 16 + fr] = f2bf(o1[i]);
    }
  }
}

// -----------------------------------------------------------------------------
extern "C" void kernel_launch(void* const* d_in, const int* in_sizes, int n_in,
                              void* d_out, int out_size, void* d_ws, size_t ws_size,
                              hipStream_t stream)
{
  const float* x_in = (const float*)d_in[0];
  const float* Wq  = (const float*)d_in[1];
  const float* Wk  = (const float*)d_in[2];
  const float* Wv  = (const float*)d_in[3];
  const float* Wo  = (const float*)d_in[4];
  const float* bo  = (const float*)d_in[5];
  const float* ln1g = (const float*)d_in[6];
  const float* ln1b = (const float*)d_in[7];
  const float* W1  = (const float*)d_in[8];
  const float* b1  = (const float*)d_in[9];
  const float* W2  = (const float*)d_in[10];
  const float* b2  = (const float*)d_in[11];
  const float* ln2g = (const float*)d_in[12];
  const float* ln2b = (const float*)d_in[13];
  float* xout = (float*)d_out;   // final fp32 output (written by L3 wo_ff_fused)

  char* ws = (char*)d_ws;
  ushort* h_buf  = (ushort*)ws;  ws += (long)NROWS*EMB*2;   // LN out / attn out
  ushort* xb     = (ushort*)ws;  ws += (long)NROWS*EMB*2;   // bf16 residual (A)
  ushort* xmid   = (ushort*)ws;  ws += (long)NROWS*EMB*2;   // bf16 residual (B)
  ushort* big    = (ushort*)ws;  ws += (long)NROWS*FFD*2;   // qkv
  ushort* wqkv_t = (ushort*)ws;  ws += (long)DEPTH*QKVN*EMB*2;
  ushort* wo_t   = (ushort*)ws;  ws += (long)DEPTH*EMB*EMB*2;
  ushort* w1_t   = (ushort*)ws;  ws += (long)DEPTH*FFD*EMB*2;
  ushort* w2_t   = (ushort*)ws;  ws += (long)DEPTH*EMB*FFD*2;
  float*  kmax   = (float*)ws;   ws += (long)BATCH*EMB*4;
  float*  ksumv  = (float*)ws;   ws += (long)BATCH*EMB*4;
  float*  ctx_part = (float*)ws; ws += (long)BATCH*HEADS*32*1024*4;
  ushort* ctxT   = (ushort*)ws;  ws += (long)BATCH*HEADS*1024*2;
  float*  pmax   = (float*)ws;   ws += (long)BATCH*NCHUNK*EMB*4;
  float*  psum   = (float*)ws;   ws += (long)BATCH*NCHUNK*EMB*4;

  prep_weights<<<3072, 256, 0, stream>>>(Wq, Wk, Wv, Wo, W1, W2, wqkv_t, wo_t, w1_t, w2_t);
  ln_kernel<<<NROWS/4, 256, 0, stream>>>(x_in, ln1g, ln1b, h_buf);

  ushort* qkv = big;
  for (int L = 0; L < DEPTH; ++L){
    // QKV projection — BN=256 retile (R20), GSWAP for A-panel L2 locality
    gemm_bt<0,128,256,32,1><<<dim3(QKVN/256, NROWS/128), 512, 0, stream>>>(
        h_buf, wqkv_t + (long)L*QKVN*EMB, NROWS, QKVN, EMB, qkv);
    colstats_partial<<<dim3(NCHUNK, BATCH), 256, 0, stream>>>(qkv, pmax, psum);
    colstats_reduce<<<BATCH, 256, 0, stream>>>(pmax, psum, kmax, ksumv);
    ctx_partial<<<dim3(16, HEADS, BATCH), 256, 0, stream>>>(qkv, kmax, ctx_part);
    ctx_reduce<<<32, 256, 0, stream>>>(ctx_part, ksumv, ctxT);
    attn_out<<<NROWS/64, 256, 0, stream>>>(qkv, ctxT, h_buf);
    // Fused Wo + FF layer tail
    if (L == 0 && DEPTH > 1){
      wo_ff_fused<3,4><<<NROWS/128, 512, 0, stream>>>(
          h_buf, wo_t, w1_t, w2_t, bo, b1, b2,
          x_in, nullptr, xmid, nullptr, xb, h_buf,
          ln2g, ln2b, ln1g + EMB, ln1b + EMB);
    } else if (L + 1 < DEPTH){
      wo_ff_fused<4,4><<<NROWS/128, 512, 0, stream>>>(
          h_buf, wo_t + (long)L*EMB*EMB, w1_t + (long)L*FFD*EMB, w2_t + (long)L*EMB*FFD,
          bo + L*EMB, b1 + L*FFD, b2 + L*EMB,
          nullptr, xb, xmid, nullptr, xb, h_buf,
          ln2g + L*EMB, ln2b + L*EMB, ln1g + (L+1)*EMB, ln1b + (L+1)*EMB);
    } else {
      wo_ff_fused<4,5><<<NROWS/128, 512, 0, stream>>>(
          h_buf, wo_t + (long)L*EMB*EMB, w1_t + (long)L*FFD*EMB, w2_t + (long)L*EMB*FFD,
          bo + L*EMB, b1 + L*FFD, b2 + L*EMB,
          nullptr, xb, xmid, xout, nullptr, nullptr,
          ln2g + L*EMB, ln2b + L*EMB, nullptr, nullptr);
    }
  }
}

// Round 22
// 566.388 us; speedup vs baseline: 1.1211x; 1.1211x over previous
//
#include <hip/hip_runtime.h>
#include <hip/hip_bf16.h>

typedef __attribute__((ext_vector_type(8))) short bf16x8;
typedef __attribute__((ext_vector_type(4))) float f32x4;

#define EMB 256
#define HEADS 8
#define DH 32
#define SEQ 8192
#define BATCH 4
#define NROWS (SEQ*BATCH)
#define FFD 1024
#define DEPTH 4
#define QKVN 768
#define SCALE 0.42044820762685725f
#define NCHUNK 128
#define ROWS_PER_CHUNK (SEQ/NCHUNK)

static __device__ __forceinline__ float bf2f(ushort u){
  union { unsigned int i; float f; } x; x.i = ((unsigned int)u) << 16; return x.f;
}
static __device__ __forceinline__ ushort f2bf(float f){
  union { __hip_bfloat16 h; ushort u; } cv;
  cv.h = __float2bfloat16(f);
  return cv.u;
}
// tanh-form GELU via one v_exp. |err| <= ~3e-3, negligible vs 0.104 threshold.
static __device__ __forceinline__ float gelu_f(float v){
  float y = 0.7978845608028654f * (v + 0.044715f*v*v*v);
  float e = __expf(2.0f*y);
  return 0.5f*v*(1.0f + (1.0f - 2.0f/(e + 1.0f)));
}

// direct HBM->LDS 16B DMA. LDS dest lane-linear; global src pre-swizzled
// (rule #21 both-sides form — validated R4-R20, absmax unchanged).
static __device__ __forceinline__ void gload_lds16(const ushort* g, ushort* l){
  __builtin_amdgcn_global_load_lds(
      (const __attribute__((address_space(1))) unsigned int*)(uintptr_t)g,
      (__attribute__((address_space(3))) unsigned int*)(uintptr_t)l,
      16, 0, 0);
}

// ---------------- weight prep: transpose fp32 [K,N] -> bf16 [N,K] -------------
__global__ __launch_bounds__(256) void prep_weights(
    const float* __restrict__ Wq, const float* __restrict__ Wk,
    const float* __restrict__ Wv, const float* __restrict__ Wo,
    const float* __restrict__ W1, const float* __restrict__ W2,
    ushort* __restrict__ wqkv_t, ushort* __restrict__ wo_t,
    ushort* __restrict__ w1_t, ushort* __restrict__ w2_t)
{
  __shared__ float tile[32][33];
  int bid = blockIdx.x;
  int L = bid / 768, r = bid % 768;
  const float* src; ushort* dst; int K, N, tidx;
  if (r < 192){ int which = r >> 6; tidx = r & 63;
    src = (which==0?Wq:which==1?Wk:Wv) + (long)L*65536;
    dst = wqkv_t + (long)L*QKVN*EMB + which*EMB*EMB; K=256; N=256;
  } else if (r < 256){ tidx = r-192; src = Wo + (long)L*65536; dst = wo_t + (long)L*65536; K=256; N=256; }
  else if (r < 512){ tidx = r-256; src = W1 + (long)L*262144; dst = w1_t + (long)L*262144; K=256; N=1024; }
  else { tidx = r-512; src = W2 + (long)L*262144; dst = w2_t + (long)L*262144; K=1024; N=256; }
  int tn = N >> 5;
  int tk = tidx / tn, tj = tidx % tn;
  int k0 = tk*32, n0 = tj*32;
  int c = threadIdx.x & 31, r0 = threadIdx.x >> 5;
  #pragma unroll
  for (int i=0;i<4;i++){
    int rr = r0 + i*8;
    tile[rr][c] = src[(long)(k0+rr)*N + n0 + c];
  }
  __syncthreads();
  #pragma unroll
  for (int i=0;i<4;i++){
    int rr = r0 + i*8;
    dst[(long)(n0+rr)*K + k0 + c] = f2bf(tile[c][rr]);
  }
}

// ---------------- layernorm (layer-0 prologue only) ---------------------------
__global__ __launch_bounds__(256) void ln_kernel(const float* __restrict__ x,
    const float* __restrict__ g, const float* __restrict__ bb,
    ushort* __restrict__ h)
{
  int wid = threadIdx.x >> 6, lane = threadIdx.x & 63;
  long row = (long)blockIdx.x*4 + wid;
  const float4 xv = *(const float4*)(x + row*EMB + lane*4);
  float s = xv.x+xv.y+xv.z+xv.w;
  float s2 = xv.x*xv.x+xv.y*xv.y+xv.z*xv.z+xv.w*xv.w;
  #pragma unroll
  for (int m=1;m<64;m<<=1){ s += __shfl_xor(s,m,64); s2 += __shfl_xor(s2,m,64); }
  float mean = s * (1.0f/EMB);
  float inv = rsqrtf(s2*(1.0f/EMB) - mean*mean + 1e-5f);
  float4 gv = *(const float4*)(g + lane*4);
  float4 bv = *(const float4*)(bb + lane*4);
  ushort4 o;
  o.x = f2bf((xv.x-mean)*inv*gv.x + bv.x);
  o.y = f2bf((xv.y-mean)*inv*gv.y + bv.y);
  o.z = f2bf((xv.z-mean)*inv*gv.z + bv.z);
  o.w = f2bf((xv.w-mean)*inv*gv.w + bv.w);
  *(ushort4*)(h + row*EMB + lane*4) = o;
}

// ---------------- GEMM: C[M,N] = A[M,K] @ Bt[N,K]^T (bf16 in, fp32 acc) ------
// Proven R13 structure. GSWAP=1: grid axes swapped so consecutive blocks share
// the A-row-panel (L2 locality). Epilogue loop-invariant loads hoisted.
template<int MODE, int BM, int BN, int BK, int GSWAP>
__global__ __launch_bounds__(512, 2) void gemm_bt(
    const ushort* __restrict__ A, const ushort* __restrict__ Bt,
    int M, int N, int K,
    const float* __restrict__ bias,
    const float* __restrict__ xinf, const ushort* __restrict__ xinb,
    float* __restrict__ xoutf, ushort* __restrict__ xoutb,
    ushort* __restrict__ outb,
    const float* __restrict__ lng, const float* __restrict__ lnb)
{
  constexpr int NF = BN/64;
  constexpr int MR = BM/32;
  constexpr int MH = MR/4;
  constexpr int KK = BK/32;
  constexpr int CPR = BK/8;
  constexpr int AI = BM*BK/4096;
  constexpr int BI = BN*BK/4096;
  constexpr int TI = AI + BI;
  constexpr int NPH = KK*MH;
  __shared__ ushort LDSraw[2*BM*BK + 2*BN*BK];
  ushort* Abuf0 = LDSraw;
  ushort* Abuf1 = LDSraw + BM*BK;
  ushort* Bbuf0 = LDSraw + 2*BM*BK;
  ushort* Bbuf1 = LDSraw + 2*BM*BK + BN*BK;
  int t = threadIdx.x;
  int lane = t & 63, wid = t >> 6;
  int wr = wid >> 2, wc = wid & 3;
  int wrb = wr*(BM/2), wcb = wc*(BN/4);
  long rowA0, colB0;
  if (GSWAP){ rowA0 = (long)blockIdx.y * BM; colB0 = (long)blockIdx.x * BN; }
  else      { rowA0 = (long)blockIdx.x * BM; colB0 = (long)blockIdx.y * BN; }
  const ushort* gA[AI]; int dA[AI];
  #pragma unroll
  for (int i=0;i<AI;i++){
    int l = i*512 + t;
    int row = l / CPR;
    int clog = (t % CPR) ^ (row & (CPR-1));
    gA[i] = A + (rowA0 + row)*(long)K + clog*8;
    dA[i] = l*8;
  }
  const ushort* gB[BI]; int dB[BI];
  #pragma unroll
  for (int i=0;i<BI;i++){
    int l = i*512 + t;
    int row = l / CPR;
    int clog = (t % CPR) ^ (row & (CPR-1));
    gB[i] = Bt + (colB0 + row)*(long)K + clog*8;
    dB[i] = l*8;
  }
  ushort* Ac = Abuf0; ushort* An = Abuf1;
  ushort* Bc = Bbuf0; ushort* Bn = Bbuf1;
  f32x4 acc[MR][NF] = {};
  int fr = lane & 15, cr4 = lane >> 4;
  int nsteps = K / BK;
  #pragma unroll
  for (int i=0;i<AI;i++) gload_lds16(gA[i], Ac + dA[i]);
  #pragma unroll
  for (int i=0;i<BI;i++) gload_lds16(gB[i], Bc + dB[i]);
  asm volatile("s_waitcnt vmcnt(0)" ::: "memory");
  __syncthreads();
  for (int s = 0; s < nsteps; ++s){
    bool pf = (s+1 < nsteps);
    long knext = (long)(s+1) * BK;
    #pragma unroll
    for (int kk=0; kk<KK; ++kk){
      int chunk = (((kk*4 + cr4)) ^ (fr & (CPR-1))) << 3;
      bf16x8 bv[NF];
      #pragma unroll
      for (int n=0;n<NF;n++)
        bv[n] = *(const bf16x8*)(Bc + (wcb + n*16 + fr)*BK + chunk);
      #pragma unroll
      for (int mh=0; mh<MH; ++mh){
        int sp = kk*MH + mh;
        bf16x8 av[4];
        #pragma unroll
        for (int m=0;m<4;m++)
          av[m] = *(const bf16x8*)(Ac + (wrb + (mh*4+m)*16 + fr)*BK + chunk);
        if (pf){
          #pragma unroll
          for (int j=0;j<TI;j++){
            if (j*NPH >= sp*TI && j*NPH < (sp+1)*TI){
              if (j < AI) gload_lds16(gA[j]+knext, An+dA[j]);
              else        gload_lds16(gB[j-AI]+knext, Bn+dB[j-AI]);
            }
          }
        }
        __builtin_amdgcn_s_setprio(1);
        #pragma unroll
        for (int m=0;m<4;m++){
          #pragma unroll
          for (int n=0;n<NF;n++)
            acc[mh*4+m][n] = __builtin_amdgcn_mfma_f32_16x16x32_bf16(av[m], bv[n], acc[mh*4+m][n], 0,0,0);
        }
        __builtin_amdgcn_s_setprio(0);
      }
    }
    asm volatile("s_waitcnt vmcnt(0)" ::: "memory");
    __syncthreads();
    ushort* tp;
    tp = Ac; Ac = An; An = tp;
    tp = Bc; Bc = Bn; Bn = tp;
  }
  constexpr int BNP = BN + 4;
  constexpr int ROUNDS = BM/32;
  constexpr int RPH = BM/64;
  float* bounce = (float*)LDSraw;
  int fq = lane >> 4;
  constexpr int TPR = BN/4;
  int rdrow = t / TPR;
  int rdcol = (t % TPR) * 4;
  constexpr int RPP = 512 / TPR;
  constexpr int PASSES = 32 / RPP;
  // hoist loop-invariant epilogue operands (gc is fixed per thread)
  long gcf = colB0 + rdcol;
  float4 bv4e = {0,0,0,0}, g4e = {0,0,0,0}, b4e = {0,0,0,0};
  if (MODE==2 || MODE==3 || MODE==4) bv4e = *(const float4*)&bias[gcf];
  if (MODE==3 || MODE==4){ g4e = *(const float4*)&lng[gcf]; b4e = *(const float4*)&lnb[gcf]; }
  #pragma unroll
  for (int r = 0; r < ROUNDS; ++r){
    __syncthreads();
    if (wr == r / RPH){
      int mb = (r % RPH)*2;
      #pragma unroll
      for (int m4=0;m4<2;m4++){
        #pragma unroll
        for (int n=0;n<NF;n++){
          #pragma unroll
          for (int i=0;i<4;i++)
            bounce[(m4*16 + fq*4 + i)*BNP + wcb + n*16 + fr] = acc[mb+m4][n][i];
        }
      }
    }
    __syncthreads();
    long gr0 = rowA0 + r*32;
    #pragma unroll
    for (int p=0;p<PASSES;p++){
      int lr = p*RPP + rdrow;
      long gr = gr0 + lr;
      float4 v = *(float4*)&bounce[lr*BNP + rdcol];
      if (MODE==0){
        ushort4 o; o.x=f2bf(v.x); o.y=f2bf(v.y); o.z=f2bf(v.z); o.w=f2bf(v.w);
        *(ushort4*)&outb[gr*N + gcf] = o;
      } else if (MODE==2){
        ushort4 o;
        o.x = f2bf(gelu_f(v.x + bv4e.x)); o.y = f2bf(gelu_f(v.y + bv4e.y));
        o.z = f2bf(gelu_f(v.z + bv4e.z)); o.w = f2bf(gelu_f(v.w + bv4e.w));
        *(ushort4*)&outb[gr*N + gcf] = o;
      } else {  // MODE 3/4: residual add + fused LN. BN==256, 1 wave/row
        float xo0, xo1, xo2, xo3;
        if (MODE==3){
          const float4 xo = *(const float4*)&xinf[gr*N + gcf];
          xo0=xo.x; xo1=xo.y; xo2=xo.z; xo3=xo.w;
        } else {
          const ushort4 xb = *(const ushort4*)&xinb[gr*N + gcf];
          xo0=bf2f(xb.x); xo1=bf2f(xb.y); xo2=bf2f(xb.z); xo3=bf2f(xb.w);
        }
        v.x += bv4e.x + xo0; v.y += bv4e.y + xo1;
        v.z += bv4e.z + xo2; v.w += bv4e.w + xo3;
        ushort4 xw;
        xw.x=f2bf(v.x); xw.y=f2bf(v.y); xw.z=f2bf(v.z); xw.w=f2bf(v.w);
        *(ushort4*)&xoutb[gr*N + gcf] = xw;
        float s1 = v.x+v.y+v.z+v.w;
        float s2 = v.x*v.x+v.y*v.y+v.z*v.z+v.w*v.w;
        #pragma unroll
        for (int mm=1;mm<64;mm<<=1){ s1 += __shfl_xor(s1,mm,64); s2 += __shfl_xor(s2,mm,64); }
        float mean = s1 * (1.0f/EMB);
        float inv = rsqrtf(s2*(1.0f/EMB) - mean*mean + 1e-5f);
        ushort4 o;
        o.x = f2bf((v.x-mean)*inv*g4e.x + b4e.x);
        o.y = f2bf((v.y-mean)*inv*g4e.y + b4e.y);
        o.z = f2bf((v.z-mean)*inv*g4e.z + b4e.z);
        o.w = f2bf((v.w-mean)*inv*g4e.w + b4e.w);
        *(ushort4*)&outb[gr*EMB + gcf] = o;
      }
    }
  }
}

// ---------------- fused FF: x += W2@gelu(W1@h + b1) + b2 (+ LN-next) ---------
// R15 (best-known): A resident in LDS; W2b issues front-loaded (kk 0-3),
// W1b(j+1) issues all at kk2==0, b1 loads hoisted, epilogue loads hoisted.
template<int MODE>   // 4: bf16 residual in/out + h=LN; 5: fp32 final out, no LN
__global__ __launch_bounds__(512) void ff_fused(
    const ushort* __restrict__ A, const ushort* __restrict__ w1t,
    const ushort* __restrict__ w2t,
    const float* __restrict__ b1, const float* __restrict__ b2,
    const ushort* __restrict__ xinb,
    float* __restrict__ xoutf, ushort* __restrict__ xoutb,
    ushort* __restrict__ hout,
    const float* __restrict__ lng, const float* __restrict__ lnb)
{
  __shared__ ushort As[128*256];     // 64 KB resident; reused as f32 bounce
  __shared__ ushort W1b[64*256];     // 32 KB
  __shared__ ushort W2b[256*64];     // 32 KB
  __shared__ ushort Ps[128*68];      // 17 KB (pad 68 -> 136B row stride)
  int t = threadIdx.x, lane = t & 63, wid = t >> 6;
  int fr = lane & 15, cr4 = lane >> 4, fq = lane >> 4;
  long rowA0 = (long)blockIdx.x * 128;
  // prologue: stage A (once) + W1c(0)
  #pragma unroll
  for (int i=0;i<8;i++){
    int l = i*512 + t;
    int row = l >> 5;
    int clog = (l & 31) ^ (row & 31);
    gload_lds16(A + (rowA0+row)*256 + clog*8, As + l*8);
  }
  #pragma unroll
  for (int i=0;i<4;i++){
    int l = i*512 + t;
    int row = l >> 5;
    int clog = (l & 31) ^ (row & 31);
    gload_lds16(w1t + row*256 + clog*8, W1b + l*8);
  }
  asm volatile("s_waitcnt vmcnt(0)" ::: "memory");
  __syncthreads();
  int rwP = (wid & 3)*32, fwP = (wid >> 2)*32;   // P-GEMM: [128 rows][64 ff]
  int rw2 = (wid >> 2)*64, cw2 = (wid & 3)*64;   // C2-GEMM: [128 rows][256 emb]
  f32x4 accC[4][4] = {};
  for (int j = 0; j < 16; ++j){
    // -------- phase P: P(j) = gelu(A @ W1c(j)^T + b1); stage W2c(j) --------
    float bvp0 = b1[j*64 + fwP + fr];
    float bvp1 = b1[j*64 + fwP + 16 + fr];
    f32x4 accP[2][2] = {};
    #pragma unroll
    for (int kk=0; kk<8; ++kk){
      if (kk < 4){                           // front-load all 4 W2c issues
        int l = kk*512 + t;
        int row = l >> 3, c = l & 7;
        int clog = c ^ (row & 7);
        gload_lds16(w2t + row*1024 + j*64 + clog*8, W2b + l*8);
      }
      int ci = kk*4 + cr4;                   // logical chunk 0..31
      bf16x8 av[2], wv[2];
      #pragma unroll
      for (int m=0;m<2;m++){
        int row = rwP + m*16 + fr;
        av[m] = *(const bf16x8*)(As + row*256 + ((ci ^ (row&31)) << 3));
      }
      #pragma unroll
      for (int n=0;n<2;n++){
        int row = fwP + n*16 + fr;
        wv[n] = *(const bf16x8*)(W1b + row*256 + ((ci ^ (row&31)) << 3));
      }
      __builtin_amdgcn_s_setprio(1);
      #pragma unroll
      for (int m=0;m<2;m++){
        #pragma unroll
        for (int n=0;n<2;n++)
          accP[m][n] = __builtin_amdgcn_mfma_f32_16x16x32_bf16(av[m], wv[n], accP[m][n], 0,0,0);
      }
      __builtin_amdgcn_s_setprio(0);
    }
    #pragma unroll
    for (int n=0;n<2;n++){
      float bv = (n==0) ? bvp0 : bvp1;
      #pragma unroll
      for (int m=0;m<2;m++){
        #pragma unroll
        for (int i2=0;i2<4;i2++){
          int row = rwP + m*16 + fq*4 + i2;
          Ps[row*68 + fwP + n*16 + fr] = f2bf(gelu_f(accP[m][n][i2] + bv));
        }
      }
    }
    asm volatile("s_waitcnt vmcnt(0)" ::: "memory");
    __syncthreads();
    // -------- phase C: C2 += P(j) @ W2c(j)^T; stage W1c(j+1) --------
    bool pw1 = (j+1 < 16);
    #pragma unroll
    for (int kk2=0; kk2<2; ++kk2){
      if (pw1 && kk2==0){                    // front-load all 4 W1c issues
        #pragma unroll
        for (int ii=0;ii<4;ii++){
          int l = ii*512 + t;
          int row = l >> 5;
          int clog = (l & 31) ^ (row & 31);
          gload_lds16(w1t + (long)(j+1)*64*256 + row*256 + clog*8, W1b + l*8);
        }
      }
      int ci2 = kk2*4 + cr4;                 // 0..7
      bf16x8 pv[4], wv2[4];
      #pragma unroll
      for (int m=0;m<4;m++){
        int row = rw2 + m*16 + fr;
        pv[m] = *(const bf16x8*)(Ps + row*68 + ci2*8);
      }
      #pragma unroll
      for (int n=0;n<4;n++){
        int row = cw2 + n*16 + fr;
        wv2[n] = *(const bf16x8*)(W2b + row*64 + ((ci2 ^ (row&7)) << 3));
      }
      __builtin_amdgcn_s_setprio(1);
      #pragma unroll
      for (int m=0;m<4;m++){
        #pragma unroll
        for (int n=0;n<4;n++)
          accC[m][n] = __builtin_amdgcn_mfma_f32_16x16x32_bf16(pv[m], wv2[n], accC[m][n], 0,0,0);
      }
      __builtin_amdgcn_s_setprio(0);
    }
    asm volatile("s_waitcnt vmcnt(0)" ::: "memory");
    __syncthreads();
  }
  // -------- epilogue: residual + (LN) via bounce in dead As --------
  float* bounce = (float*)As;
  int rdrow = t >> 6;            // 64 threads (1 wave) per row
  int rdcol = (t & 63) * 4;
  const float4 bv4 = *(const float4*)&b2[rdcol];
  float4 g4 = {0,0,0,0}, b4 = {0,0,0,0};
  if (MODE==4){ g4 = *(const float4*)&lng[rdcol]; b4 = *(const float4*)&lnb[rdcol]; }
  #pragma unroll
  for (int r = 0; r < 4; ++r){
    __syncthreads();
    if ((wid >> 2) == (r >> 1)){
      int mb = (r & 1)*2;
      #pragma unroll
      for (int m4=0;m4<2;m4++){
        #pragma unroll
        for (int n=0;n<4;n++){
          #pragma unroll
          for (int i2=0;i2<4;i2++)
            bounce[(m4*16 + fq*4 + i2)*260 + cw2 + n*16 + fr] = accC[mb+m4][n][i2];
        }
      }
    }
    __syncthreads();
    long gr0 = rowA0 + r*32;
    #pragma unroll
    for (int p=0;p<4;p++){
      int lr = p*8 + rdrow;
      long gr = gr0 + lr;
      float4 v = *(float4*)&bounce[lr*260 + rdcol];
      const ushort4 xb4 = *(const ushort4*)&xinb[gr*EMB + rdcol];
      v.x += bv4.x + bf2f(xb4.x); v.y += bv4.y + bf2f(xb4.y);
      v.z += bv4.z + bf2f(xb4.z); v.w += bv4.w + bf2f(xb4.w);
      if (MODE==5){
        *(float4*)&xoutf[gr*EMB + rdcol] = v;
      } else {
        ushort4 xw;
        xw.x=f2bf(v.x); xw.y=f2bf(v.y); xw.z=f2bf(v.z); xw.w=f2bf(v.w);
        *(ushort4*)&xoutb[gr*EMB + rdcol] = xw;
        float s1 = v.x+v.y+v.z+v.w;
        float s2 = v.x*v.x+v.y*v.y+v.z*v.z+v.w*v.w;
        #pragma unroll
        for (int mm=1;mm<64;mm<<=1){ s1 += __shfl_xor(s1,mm,64); s2 += __shfl_xor(s2,mm,64); }
        float mean = s1 * (1.0f/EMB);
        float inv = rsqrtf(s2*(1.0f/EMB) - mean*mean + 1e-5f);
        ushort4 o;
        o.x = f2bf((v.x-mean)*inv*g4.x + b4.x);
        o.y = f2bf((v.y-mean)*inv*g4.y + b4.y);
        o.z = f2bf((v.z-mean)*inv*g4.z + b4.z);
        o.w = f2bf((v.w-mean)*inv*g4.w + b4.w);
        *(ushort4*)&hout[gr*EMB + rdcol] = o;
      }
    }
  }
}

// ---------------- k-softmax column stats, chunked over n ----------------------
__global__ __launch_bounds__(256) void colstats_partial(const ushort* __restrict__ qkv,
    float* __restrict__ pmax, float* __restrict__ psum)
{
  int ch = blockIdx.x, b = blockIdx.y;
  int t = threadIdx.x;
  const ushort* base = qkv + ((long)b*SEQ + (long)ch*ROWS_PER_CHUNK)*QKVN + EMB + t;
  float m[4] = {-1e30f,-1e30f,-1e30f,-1e30f};
  float s[4] = {0.f,0.f,0.f,0.f};
  #pragma unroll 2
  for (int n = 0; n < ROWS_PER_CHUNK; n += 4){
    #pragma unroll
    for (int j=0;j<4;j++){
      float v = bf2f(base[(long)(n+j)*QKVN]) * SCALE;
      float m2 = fmaxf(m[j], v);
      s[j] = s[j]*__expf(m[j]-m2) + __expf(v-m2);
      m[j] = m2;
    }
  }
  float M = fmaxf(fmaxf(m[0],m[1]), fmaxf(m[2],m[3]));
  float S = s[0]*__expf(m[0]-M) + s[1]*__expf(m[1]-M)
          + s[2]*__expf(m[2]-M) + s[3]*__expf(m[3]-M);
  long idx = ((long)b*NCHUNK + ch)*EMB + t;
  pmax[idx] = M; psum[idx] = S;
}

__global__ __launch_bounds__(256) void colstats_reduce(const float* __restrict__ pmax,
    const float* __restrict__ psum, float* __restrict__ kmax, float* __restrict__ ksum)
{
  int b = blockIdx.x, t = threadIdx.x;
  const float* pm = pmax + (long)b*NCHUNK*EMB + t;
  const float* ps = psum + (long)b*NCHUNK*EMB + t;
  float m = -1e30f, s = 0.f;
  for (int c = 0; c < NCHUNK; ++c){
    float cm = pm[(long)c*EMB], cs = ps[(long)c*EMB];
    float m2 = fmaxf(m, cm);
    s = s*__expf(m-m2) + cs*__expf(cm-m2);
    m = m2;
  }
  kmax[b*EMB + t] = m;
  ksum[b*EMB + t] = s;
}

// ---------------- context partials: ctx_part[b][h][chunk][d][e] --------------
__global__ __launch_bounds__(256) void ctx_partial(
    const ushort* __restrict__ qkv, const float* __restrict__ kmax,
    float* __restrict__ ctx_part)
{
  constexpr int LT = 72;
  __shared__ ushort ekT[32*LT];
  __shared__ ushort vvT[32*LT];
  int ch = blockIdx.x, h = blockIdx.y, b = blockIdx.z;
  int t = threadIdx.x, lane = t & 63, wid = t >> 6;
  long nbase = (long)b*SEQ + ch*512;
  int lrow = t >> 2, lseg = (t & 3) << 3;
  float km[8];
  #pragma unroll
  for (int j=0;j<8;j++) km[j] = kmax[b*256 + h*DH + lseg + j];
  int wstep = wid & 1, wdr = (wid >> 1) << 4;
  f32x4 acc0 = {}, acc1 = {};
  int frow = lane & 15, g8 = (lane >> 4) << 3;
  for (int st = 0; st < 8; ++st){
    long n0 = nbase + st*64;
    const ushort* gk = qkv + (n0 + lrow)*QKVN + EMB + h*DH + lseg;
    uint4 kv = *(const uint4*)gk;
    uint4 vv = *(const uint4*)(gk + EMB);
    __syncthreads();
    const ushort* kp = (const ushort*)&kv;
    const ushort* vp = (const ushort*)&vv;
    #pragma unroll
    for (int j=0;j<8;j++){
      float f = bf2f(kp[j])*SCALE;
      ekT[(lseg+j)*LT + lrow] = f2bf(__expf(f - km[j]));
      vvT[(lseg+j)*LT + lrow] = vp[j];
    }
    __syncthreads();
    bf16x8 afr = *(const bf16x8*)(ekT + (wdr + frow)*LT + wstep*32 + g8);
    bf16x8 bf0 = *(const bf16x8*)(vvT + frow*LT + wstep*32 + g8);
    bf16x8 bf1 = *(const bf16x8*)(vvT + (16 + frow)*LT + wstep*32 + g8);
    acc0 = __builtin_amdgcn_mfma_f32_16x16x32_bf16(afr, bf0, acc0, 0,0,0);
    acc1 = __builtin_amdgcn_mfma_f32_16x16x32_bf16(afr, bf1, acc1, 0,0,0);
  }
  int fq = lane >> 4;
  long pb = (((long)(b*HEADS+h))*32 + (ch*2+wstep))*1024;
  #pragma unroll
  for (int i=0;i<4;i++){
    ctx_part[pb + (wdr + fq*4 + i)*32 + frow] = acc0[i];
    ctx_part[pb + (wdr + fq*4 + i)*32 + 16 + frow] = acc1[i];
  }
}

// ---------------- context reduce + 1/ksum + write transposed bf16 ------------
__global__ __launch_bounds__(256) void ctx_reduce(const float* __restrict__ ctx_part,
    const float* __restrict__ ksum, ushort* __restrict__ ctxT)
{
  int bh = blockIdx.x; int b = bh >> 3, h = bh & 7;
  int t = threadIdx.x; int d = t >> 3, e4 = (t & 7) << 2;
  const float* p = ctx_part + (long)bh*32768 + d*32 + e4;
  float sx=0, sy=0, sz=0, sw=0;
  for (int c=0;c<32;c++){
    const float4 v = *(const float4*)(p + c*1024);
    sx+=v.x; sy+=v.y; sz+=v.z; sw+=v.w;
  }
  float inv = 1.0f / ksum[b*256 + h*DH + d];
  long base = (long)bh*1024;
  ctxT[base + (e4+0)*32 + d] = f2bf(sx*inv);
  ctxT[base + (e4+1)*32 + d] = f2bf(sy*inv);
  ctxT[base + (e4+2)*32 + d] = f2bf(sz*inv);
  ctxT[base + (e4+3)*32 + d] = f2bf(sw*inv);
}

// ---------------- q-softmax @ ctx -> ao (bf16) -------------------------------
__global__ __launch_bounds__(256) void attn_out(
    const ushort* __restrict__ qkv, const ushort* __restrict__ ctxT,
    ushort* __restrict__ ao)
{
  __shared__ ushort sq[4][16][264];
  int t = threadIdx.x, lane = t & 63, wid = t >> 6;
  long row0 = (long)blockIdx.x*64 + wid*16;
  int b = (int)(row0 / SEQ);
  int fr = lane & 15, g = lane >> 4;
  bf16x8 cf[8][2];
  #pragma unroll
  for (int h=0;h<8;h++){
    #pragma unroll
    for (int eh=0;eh<2;eh++)
      cf[h][eh] = *(const bf16x8*)(ctxT + ((long)(b*8+h)*32 + eh*16 + fr)*32 + g*8);
  }
  long gr = row0 + fr;
  #pragma unroll
  for (int hh=0;hh<2;hh++){
    int h = g*2 + hh;
    const ushort* qp = qkv + gr*QKVN + h*DH;
    union { uint4 v[4]; ushort u[32]; } qq;
    qq.v[0]=*(const uint4*)qp; qq.v[1]=*(const uint4*)(qp+8);
    qq.v[2]=*(const uint4*)(qp+16); qq.v[3]=*(const uint4*)(qp+24);
    float f[32]; float m = -1e30f;
    #pragma unroll
    for (int j=0;j<32;j++){ f[j] = bf2f(qq.u[j])*SCALE; m = fmaxf(m, f[j]); }
    float ssum = 0.f;
    #pragma unroll
    for (int j=0;j<32;j++){ f[j] = __expf(f[j]-m); ssum += f[j]; }
    float inv = 1.0f/ssum;
    union { uint4 v[4]; ushort u[32]; } oo;
    #pragma unroll
    for (int j=0;j<32;j++) oo.u[j] = f2bf(f[j]*inv);
    ushort* dst = &sq[wid][fr][h*DH];
    #pragma unroll
    for (int c2=0;c2<4;c2++) *(uint4*)(dst + c2*8) = oo.v[c2];
  }
  __syncthreads();
  #pragma unroll
  for (int h=0;h<8;h++){
    bf16x8 af = *(const bf16x8*)(&sq[wid][fr][h*DH + g*8]);
    f32x4 z = {};
    f32x4 o0 = __builtin_amdgcn_mfma_f32_16x16x32_bf16(af, cf[h][0], z, 0,0,0);
    f32x4 o1 = __builtin_amdgcn_mfma_f32_16x16x32_bf16(af, cf[h][1], z, 0,0,0);
    #pragma unroll
    for (int i=0;i<4;i++){
      long r = row0 + g*4 + i;
      ao[r*EMB + h*DH + fr]      = f2bf(o0[i]);
      ao[r*EMB + h*DH + 16 + fr] = f2bf(o1[i]);
    }
  }
}

// -----------------------------------------------------------------------------
extern "C" void kernel_launch(void* const* d_in, const int* in_sizes, int n_in,
                              void* d_out, int out_size, void* d_ws, size_t ws_size,
                              hipStream_t stream)
{
  const float* x_in = (const float*)d_in[0];
  const float* Wq  = (const float*)d_in[1];
  const float* Wk  = (const float*)d_in[2];
  const float* Wv  = (const float*)d_in[3];
  const float* Wo  = (const float*)d_in[4];
  const float* bo  = (const float*)d_in[5];
  const float* ln1g = (const float*)d_in[6];
  const float* ln1b = (const float*)d_in[7];
  const float* W1  = (const float*)d_in[8];
  const float* b1  = (const float*)d_in[9];
  const float* W2  = (const float*)d_in[10];
  const float* b2  = (const float*)d_in[11];
  const float* ln2g = (const float*)d_in[12];
  const float* ln2b = (const float*)d_in[13];
  float* xout = (float*)d_out;   // final fp32 output (written by L3 ff_fused)

  char* ws = (char*)d_ws;
  ushort* h_buf  = (ushort*)ws;  ws += (long)NROWS*EMB*2;   // LN out / attn out
  ushort* xb     = (ushort*)ws;  ws += (long)NROWS*EMB*2;   // bf16 residual stream
  ushort* big    = (ushort*)ws;  ws += (long)NROWS*FFD*2;   // qkv
  ushort* wqkv_t = (ushort*)ws;  ws += (long)DEPTH*QKVN*EMB*2;
  ushort* wo_t   = (ushort*)ws;  ws += (long)DEPTH*EMB*EMB*2;
  ushort* w1_t   = (ushort*)ws;  ws += (long)DEPTH*FFD*EMB*2;
  ushort* w2_t   = (ushort*)ws;  ws += (long)DEPTH*EMB*FFD*2;
  float*  kmax   = (float*)ws;   ws += (long)BATCH*EMB*4;
  float*  ksumv  = (float*)ws;   ws += (long)BATCH*EMB*4;
  float*  ctx_part = (float*)ws; ws += (long)BATCH*HEADS*32*1024*4;
  ushort* ctxT   = (ushort*)ws;  ws += (long)BATCH*HEADS*1024*2;
  float*  pmax   = (float*)ws;   ws += (long)BATCH*NCHUNK*EMB*4;
  float*  psum   = (float*)ws;   ws += (long)BATCH*NCHUNK*EMB*4;

  prep_weights<<<3072, 256, 0, stream>>>(Wq, Wk, Wv, Wo, W1, W2, wqkv_t, wo_t, w1_t, w2_t);
  ln_kernel<<<NROWS/4, 256, 0, stream>>>(x_in, ln1g, ln1b, h_buf);

  ushort* qkv = big;
  for (int L = 0; L < DEPTH; ++L){
    // QKV projection — BN=256 retile: A staged 3x (was 6x), 48KB LDS, 2 blk/CU
    gemm_bt<0,128,256,32,1><<<dim3(QKVN/256, NROWS/128), 512, 0, stream>>>(
        h_buf, wqkv_t + (long)L*QKVN*EMB, NROWS, QKVN, EMB,
        nullptr, nullptr, nullptr, nullptr, nullptr, qkv, nullptr, nullptr);
    colstats_partial<<<dim3(NCHUNK, BATCH), 256, 0, stream>>>(qkv, pmax, psum);
    colstats_reduce<<<BATCH, 256, 0, stream>>>(pmax, psum, kmax, ksumv);
    ctx_partial<<<dim3(16, HEADS, BATCH), 256, 0, stream>>>(qkv, kmax, ctx_part);
    ctx_reduce<<<32, 256, 0, stream>>>(ctx_part, ksumv, ctxT);
    attn_out<<<NROWS/64, 256, 0, stream>>>(qkv, ctxT, h_buf);
    // Wo + residual + fused LN2 -> xb (bf16) and h2 (in-place h_buf)
    if (L == 0){
      gemm_bt<3,128,256,64,0><<<dim3(NROWS/128, 1), 512, 0, stream>>>(
          h_buf, wo_t, NROWS, EMB, EMB,
          bo, x_in, nullptr, nullptr, xb, h_buf, ln2g, ln2b);
    } else {
      gemm_bt<4,128,256,64,0><<<dim3(NROWS/128, 1), 512, 0, stream>>>(
          h_buf, wo_t + (long)L*EMB*EMB, NROWS, EMB, EMB,
          bo + L*EMB, nullptr, xb, nullptr, xb, h_buf,
          ln2g + L*EMB, ln2b + L*EMB);
    }
    // Fused FF: x += W2@gelu(W1@h2+b1)+b2  (+ LN1-next except final layer)
    if (L + 1 < DEPTH){
      ff_fused<4><<<256, 512, 0, stream>>>(
          h_buf, w1_t + (long)L*FFD*EMB, w2_t + (long)L*EMB*FFD,
          b1 + L*FFD, b2 + L*EMB, xb, nullptr, xb, h_buf,
          ln1g + (L+1)*EMB, ln1b + (L+1)*EMB);
    } else {
      ff_fused<5><<<256, 512, 0, stream>>>(
          h_buf, w1_t + (long)L*FFD*EMB, w2_t + (long)L*EMB*FFD,
          b1 + L*FFD, b2 + L*EMB, xb, xout, nullptr, nullptr,
          nullptr, nullptr);
    }
  }
}